// Round 1
// baseline (277.211 us; speedup 1.0000x reference)
//
#include <hip/hip_runtime.h>

typedef _Float16 f16;
typedef _Float16 f16x8 __attribute__((ext_vector_type(8)));
typedef _Float16 f16x4 __attribute__((ext_vector_type(4)));
typedef float f32x4 __attribute__((ext_vector_type(4)));

#define GDIM 52
#define GG 2704          // 52*52
#define CIN 256
#define CMID 512
#define COUT 75
#define NIMG 16
#define NTILE 128
#define NB_PER_IMG 22    // ceil(2704/128)

__device__ __forceinline__ float sigmoidf_(float x) {
    return 1.0f / (1.0f + __expf(-x));
}

// ---------------- prep: x [b][ci][h][w] f32 -> x16 [b][hw][ci] f16 ----------
__global__ __launch_bounds__(256) void k_prep_x(const float* __restrict__ x,
                                                f16* __restrict__ x16) {
    __shared__ float ls[64][65];
    int hw0 = blockIdx.x * 64, ci0 = blockIdx.y * 64, img = blockIdx.z;
    int tid = threadIdx.x;
    int r0 = tid >> 4;        // 0..15
    int c4 = (tid & 15) * 4;  // 0..60
    const float* xb = x + ((size_t)img * CIN + ci0) * GG;
#pragma unroll
    for (int it = 0; it < 4; ++it) {
        int r = r0 + it * 16;  // ci local
#pragma unroll
        for (int k = 0; k < 4; ++k) {
            int hw = hw0 + c4 + k;
            ls[r][c4 + k] = (hw < GG) ? xb[(size_t)r * GG + hw] : 0.0f;
        }
    }
    __syncthreads();
#pragma unroll
    for (int it = 0; it < 4; ++it) {
        int s = r0 + it * 16;  // hw local
        int hw = hw0 + s;
        if (hw < GG) {
            f16x4 o;
#pragma unroll
            for (int k = 0; k < 4; ++k) o[k] = (f16)ls[c4 + k][s];
            *(f16x4*)(x16 + ((size_t)img * GG + hw) * CIN + ci0 + c4) = o;
        }
    }
}

// ---------------- prep: weights + BN fold ----------------
__global__ __launch_bounds__(256) void k_prep_w(
    const float* __restrict__ w1, const float* __restrict__ w2,
    const float* __restrict__ gamma, const float* __restrict__ beta,
    const float* __restrict__ mean, const float* __restrict__ var,
    f16* __restrict__ w16, f16* __restrict__ w2_16,
    float* __restrict__ bnscale, float* __restrict__ bnshift) {
    int gid = blockIdx.x * 256 + threadIdx.x;
    int gsz = gridDim.x * 256;
    for (int i = gid; i < CMID * CIN * 9; i += gsz) {
        int co = i / 2304, r = i % 2304;
        int tap = r >> 8, ci = r & 255;
        w16[i] = (f16)w1[co * 2304 + ci * 9 + tap];  // out layout [co][tap][ci]
    }
    if (gid < COUT * CMID) w2_16[gid] = (f16)w2[gid];
    if (gid < CMID) {
        float s = gamma[gid] * rsqrtf(var[gid] + 1e-5f);
        bnscale[gid] = s;
        bnshift[gid] = beta[gid] - mean[gid] * s;
    }
}

// ---------------- conv1: 3x3 + BN + LeakyReLU -> y16 [b][hw][co] ------------
// block: 128 co x 128 spatial, 4 waves (2m x 2n), wave tile 64co x 64sp.
__global__ __launch_bounds__(256, 3) void k_conv1(
    const f16* __restrict__ x16, const f16* __restrict__ w16,
    const float* __restrict__ bnscale, const float* __restrict__ bnshift,
    f16* __restrict__ y16) {
    __shared__ f16x8 xs[6 * 54 * 4];  // 20736 B, [row][col][4 swizzled 16B ci-slots]
    int img = blockIdx.x / NB_PER_IMG;
    int n0 = (blockIdx.x % NB_PER_IMG) * NTILE;
    int co0 = blockIdx.y * 128;
    int tid = threadIdx.x;
    int lane = tid & 63, wave = tid >> 6;
    int wm = wave >> 1, wn = wave & 1;
    int l15 = lane & 15, kg = lane >> 4;
    int h_lo = n0 / GDIM;

    int hh[4], ww[4];
    bool vn[4];
#pragma unroll
    for (int nf = 0; nf < 4; ++nf) {
        int n = n0 + wn * 64 + nf * 16 + l15;
        vn[nf] = n < GG;
        int nc = vn[nf] ? n : GG - 1;
        hh[nf] = nc / GDIM;
        ww[nf] = nc % GDIM;
    }

    f32x4 acc[4][4];
#pragma unroll
    for (int a = 0; a < 4; ++a)
#pragma unroll
        for (int b = 0; b < 4; ++b) {
            acc[a][b][0] = 0.f; acc[a][b][1] = 0.f;
            acc[a][b][2] = 0.f; acc[a][b][3] = 0.f;
        }

    const f16* xb = x16 + (size_t)img * GG * CIN;
    const f16* wb = w16 + (size_t)(co0 + wm * 64 + l15) * 2304 + kg * 8;

    for (int c0 = 0; c0 < CIN; c0 += 32) {
        // stage 6 rows x 54 cols x 32 ci (zero-padded halo), swizzled slots
        for (int u = tid; u < 6 * 54 * 4; u += 256) {
            int r = u / 216, rem = u % 216;
            int c = rem >> 2, s = rem & 3;
            int h = h_lo - 1 + r, w = c - 1;
            f16x8 v;
            if ((unsigned)h < GDIM && (unsigned)w < GDIM)
                v = *(const f16x8*)(xb + (size_t)(h * GDIM + w) * CIN + c0 + s * 8);
            else {
#pragma unroll
                for (int k = 0; k < 8; ++k) v[k] = (f16)0;
            }
            xs[(r * 54 + c) * 4 + (s ^ (c & 3))] = v;
        }
        __syncthreads();
#pragma unroll
        for (int tap = 0; tap < 9; ++tap) {
            int dh = tap / 3 - 1, dw = tap % 3 - 1;
            f16x8 af[4];
            const f16* wt = wb + tap * 256 + c0;
#pragma unroll
            for (int mf = 0; mf < 4; ++mf)
                af[mf] = *(const f16x8*)(wt + (size_t)mf * 16 * 2304);
#pragma unroll
            for (int nf = 0; nf < 4; ++nf) {
                int r = hh[nf] - h_lo + 1 + dh;
                int c = ww[nf] + 1 + dw;
                f16x8 bf = xs[(r * 54 + c) * 4 + (kg ^ (c & 3))];
#pragma unroll
                for (int mf = 0; mf < 4; ++mf)
                    acc[mf][nf] = __builtin_amdgcn_mfma_f32_16x16x32_f16(
                        af[mf], bf, acc[mf][nf], 0, 0, 0);
            }
        }
        __syncthreads();
    }
    // epilogue: BN + leaky, store fp16 (co = cob + i at spatial n)
#pragma unroll
    for (int mf = 0; mf < 4; ++mf) {
        int cob = co0 + wm * 64 + mf * 16 + kg * 4;
        f32x4 sc = *(const f32x4*)(bnscale + cob);
        f32x4 sh = *(const f32x4*)(bnshift + cob);
#pragma unroll
        for (int nf = 0; nf < 4; ++nf) {
            if (!vn[nf]) continue;
            int n = n0 + wn * 64 + nf * 16 + l15;
            f16x4 o;
#pragma unroll
            for (int i = 0; i < 4; ++i) {
                float v = acc[mf][nf][i] * sc[i] + sh[i];
                v = v > 0.f ? v : 0.1f * v;
                o[i] = (f16)v;
            }
            *(f16x4*)(y16 + ((size_t)img * GG + n) * CMID + cob) = o;
        }
    }
}

// ---------------- conv2 (1x1, K=512) + bias + YOLO decode -------------------
// block: 2 waves; wave tile 80co x 64n. No LDS in K-loop (global frags).
__global__ __launch_bounds__(128, 3) void k_conv2(
    const f16* __restrict__ y16, const f16* __restrict__ w2_16,
    const float* __restrict__ b2, float* __restrict__ out) {
    __shared__ float ct[2][64][80];  // 40 KB epilogue transpose
    int img = blockIdx.x / NB_PER_IMG;
    int n0 = (blockIdx.x % NB_PER_IMG) * NTILE;
    int tid = threadIdx.x;
    int lane = tid & 63, wave = tid >> 6;
    int l15 = lane & 15, kg = lane >> 4;
    int nwb = n0 + wave * 64;

    f32x4 acc[5][4];
#pragma unroll
    for (int a = 0; a < 5; ++a)
#pragma unroll
        for (int b = 0; b < 4; ++b) {
            acc[a][b][0] = 0.f; acc[a][b][1] = 0.f;
            acc[a][b][2] = 0.f; acc[a][b][3] = 0.f;
        }

    const f16* yb = y16 + (size_t)img * GG * CMID;
    int nn[4];
#pragma unroll
    for (int nf = 0; nf < 4; ++nf) {
        int n = nwb + nf * 16 + l15;
        nn[nf] = n < GG ? n : GG - 1;
    }
    for (int c0 = 0; c0 < CMID; c0 += 32) {
        f16x8 af[5];
#pragma unroll
        for (int mf = 0; mf < 5; ++mf) {
            int co = mf * 16 + l15;
            if (co < COUT)
                af[mf] = *(const f16x8*)(w2_16 + (size_t)co * CMID + c0 + kg * 8);
            else {
#pragma unroll
                for (int k = 0; k < 8; ++k) af[mf][k] = (f16)0;
            }
        }
#pragma unroll
        for (int nf = 0; nf < 4; ++nf) {
            f16x8 bf = *(const f16x8*)(yb + (size_t)nn[nf] * CMID + c0 + kg * 8);
#pragma unroll
            for (int mf = 0; mf < 5; ++mf)
                acc[mf][nf] = __builtin_amdgcn_mfma_f32_16x16x32_f16(
                    af[mf], bf, acc[mf][nf], 0, 0, 0);
        }
    }
    // dump accumulators to LDS: ct[wave][n_local][co]
#pragma unroll
    for (int mf = 0; mf < 5; ++mf)
#pragma unroll
        for (int nf = 0; nf < 4; ++nf)
            *(f32x4*)(&ct[wave][nf * 16 + l15][mf * 16 + kg * 4]) = acc[mf][nf];
    __syncthreads();
    // decode: 128 threads x 3 anchors
    for (int a = 0; a < 3; ++a) {
        int nl = tid;
        int n = n0 + nl;
        if (n >= GG) continue;
        const float* t = &ct[nl >> 6][nl & 63][a * 25];
        float tv[25];
#pragma unroll
        for (int j = 0; j < 25; ++j) tv[j] = t[j] + b2[a * 25 + j];
        int h = n / GDIM, w = n % GDIM;
        const float AW[3] = {10.f, 16.f, 33.f};
        const float AH[3] = {13.f, 30.f, 23.f};
        float bx = (sigmoidf_(tv[0]) + (float)w) * 8.0f;
        float by = (sigmoidf_(tv[1]) + (float)h) * 8.0f;
        float bw_ = __expf(tv[2]) * AW[a];
        float bh_ = __expf(tv[3]) * AH[a];
        float* o = out + ((size_t)img * 8112 + (size_t)a * GG + n) * 25;
        o[0] = bx; o[1] = by; o[2] = bw_; o[3] = bh_;
        o[4] = sigmoidf_(tv[4]);
#pragma unroll
        for (int j = 0; j < 20; ++j) o[5 + j] = sigmoidf_(tv[5 + j]);
    }
}

extern "C" void kernel_launch(void* const* d_in, const int* in_sizes, int n_in,
                              void* d_out, int out_size, void* d_ws, size_t ws_size,
                              hipStream_t stream) {
    (void)in_sizes; (void)n_in; (void)out_size; (void)ws_size;
    const float* x     = (const float*)d_in[0];
    const float* w1    = (const float*)d_in[1];
    const float* gamma = (const float*)d_in[2];
    const float* beta  = (const float*)d_in[3];
    const float* mean  = (const float*)d_in[4];
    const float* var   = (const float*)d_in[5];
    const float* w2    = (const float*)d_in[6];
    const float* b2    = (const float*)d_in[7];
    float* out = (float*)d_out;

    char* ws = (char*)d_ws;
    f16* x16      = (f16*)(ws);                 // 22,151,168 B
    f16* w16      = (f16*)(ws + 22151168);      //  2,359,296 B
    f16* w2_16    = (f16*)(ws + 24510464);      //     76,800 B
    float* bnscale = (float*)(ws + 24587264);   //      2,048 B
    float* bnshift = (float*)(ws + 24589312);   //      2,048 B
    f16* y16      = (f16*)(ws + 24591360);      // 44,302,336 B  (total ~65.7 MiB)

    k_prep_x<<<dim3(43, 4, NIMG), 256, 0, stream>>>(x, x16);
    k_prep_w<<<4608, 256, 0, stream>>>(w1, w2, gamma, beta, mean, var,
                                       w16, w2_16, bnscale, bnshift);
    k_conv1<<<dim3(NIMG * NB_PER_IMG, 4), 256, 0, stream>>>(x16, w16, bnscale,
                                                            bnshift, y16);
    k_conv2<<<NIMG * NB_PER_IMG, 128, 0, stream>>>(y16, w2_16, b2, out);
}

// Round 2
// 213.087 us; speedup vs baseline: 1.3009x; 1.3009x over previous
//
#include <hip/hip_runtime.h>

typedef _Float16 f16;
typedef _Float16 f16x8 __attribute__((ext_vector_type(8)));
typedef _Float16 f16x4 __attribute__((ext_vector_type(4)));
typedef float f32x4 __attribute__((ext_vector_type(4)));

#define GDIM 52
#define GG 2704          // 52*52
#define CIN 256
#define CMID 512
#define COUT 75
#define NIMG 16
#define SPT 192          // conv1 spatial tile
#define NSPB 15          // ceil(2704/192)
#define PH 60            // padded rows in x16p
#define PW 54            // padded cols

__device__ __forceinline__ float sigmoidf_(float x) {
    return 1.0f / (1.0f + __expf(-x));
}

__device__ __forceinline__ void gload16(const void* g, void* l) {
    __builtin_amdgcn_global_load_lds(
        (const __attribute__((address_space(1))) unsigned int*)g,
        (__attribute__((address_space(3))) unsigned int*)l, 16, 0, 0);
}

// ---- prep: x [img][ci][hw] f32 -> x16p [img][ck][h+1][w+1][32ci] f16 (padded) ----
__global__ __launch_bounds__(256) void k_prep_x(const float* __restrict__ x,
                                                f16* __restrict__ x16p) {
    __shared__ float ls[32][133];
    int hw0 = blockIdx.x * 128, ck = blockIdx.y, img = blockIdx.z;
    int tid = threadIdx.x;
    const float* xb = x + ((size_t)img * CIN + ck * 32) * GG;
#pragma unroll
    for (int i = 0; i < 16; ++i) {
        int idx = tid + i * 256;
        int r = idx >> 7, c = idx & 127;
        int hw = hw0 + c;
        ls[r][c] = (hw < GG) ? xb[(size_t)r * GG + hw] : 0.0f;
    }
    __syncthreads();
    int col = tid >> 1, half = tid & 1;
    int hw = hw0 + col;
    if (hw < GG) {
        int h = hw / GDIM, w = hw % GDIM;
        f16* dst = x16p + ((((size_t)img * 8 + ck) * PH + h + 1) * PW + (w + 1)) * 32 + half * 16;
        f16x8 o0, o1;
#pragma unroll
        for (int j = 0; j < 8; ++j) o0[j] = (f16)ls[half * 16 + j][col];
#pragma unroll
        for (int j = 0; j < 8; ++j) o1[j] = (f16)ls[half * 16 + 8 + j][col];
        *(f16x8*)dst = o0;
        *(f16x8*)(dst + 8) = o1;
    }
}

// ---- prep: weights + BN fold.  w16 layout [tap][ck][co][32ci] ----
__global__ __launch_bounds__(256) void k_prep_w(
    const float* __restrict__ w1, const float* __restrict__ w2,
    const float* __restrict__ gamma, const float* __restrict__ beta,
    const float* __restrict__ mean, const float* __restrict__ var,
    f16* __restrict__ w16, f16* __restrict__ w2_16,
    float* __restrict__ bnscale, float* __restrict__ bnshift) {
    int i = blockIdx.x * 256 + threadIdx.x;   // exactly 9*8*512*32 = 1,179,648 threads
    int cl = i & 31;
    int co = (i >> 5) & 511;
    int ckt = i >> 14;          // tap*8 + ck
    int ck = ckt & 7, tap = ckt >> 3;
    int ci = ck * 32 + cl;
    w16[i] = (f16)w1[(size_t)co * 2304 + ci * 9 + tap];
    if (i < COUT * CMID) w2_16[i] = (f16)w2[i];
    if (i < CMID) {
        float s = gamma[i] * rsqrtf(var[i] + 1e-5f);
        bnscale[i] = s;
        bnshift[i] = beta[i] - mean[i] * s;
    }
}

// ---- conv1: 3x3 + BN + LeakyReLU -> y16 [img][n][co] ----
// 512 thr / 8 waves (2 wm x 4 wn); block 256co x 192sp; wave 128co x 48sp.
__global__ __launch_bounds__(512, 2) void k_conv1(
    const f16* __restrict__ x16p, const f16* __restrict__ w16,
    const float* __restrict__ bnscale, const float* __restrict__ bnshift,
    f16* __restrict__ y16) {
    __shared__ __align__(16) f16 slab[7 * PW * 32];   // 24192 B  (7 rows halo tile)
    __shared__ __align__(16) f16 At[2][256 * 32];     // 2 x 16384 B (A double-buffer)
    int img = blockIdx.x / NSPB, sb = blockIdx.x % NSPB;
    int n0 = sb * SPT;
    int h_lo = n0 / GDIM;
    int co0 = blockIdx.y * 256;
    int tid = threadIdx.x;
    int lane = tid & 63, wave = tid >> 6;
    int wm = wave >> 2, wn = wave & 3;
    int l15 = lane & 15, kg = lane >> 4;

    int roff[3], nlist[3];
    bool vn[3];
#pragma unroll
    for (int nf = 0; nf < 3; ++nf) {
        int n = n0 + wn * 48 + nf * 16 + l15;
        vn[nf] = n < GG;
        int nc = vn[nf] ? n : GG - 1;
        nlist[nf] = n;
        int hh = nc / GDIM, ww = nc % GDIM;
        roff[nf] = ((hh - h_lo + 1) * PW + (ww + 1)) * 64 + kg * 16;  // byte off in slab
    }

    f32x4 acc[8][3];
#pragma unroll
    for (int a = 0; a < 8; ++a)
#pragma unroll
        for (int b = 0; b < 3; ++b) {
            acc[a][b][0] = 0.f; acc[a][b][1] = 0.f;
            acc[a][b][2] = 0.f; acc[a][b][3] = 0.f;
        }

    // prologue: stage A(g=0) = (tap0, ck0)
    {
        const f16* wA = w16 + (size_t)co0 * 32;
        gload16(wA + (size_t)tid * 8, &At[0][0] + (size_t)tid * 8);
        gload16(wA + (size_t)(tid + 512) * 8, &At[0][0] + (size_t)(tid + 512) * 8);
    }

    for (int ck = 0; ck < 8; ++ck) {
        __syncthreads();   // prev ck's compute done -> slab free; full drain ok
        // stage slab(ck): 1512 x 16B contiguous
        const f16* sg = x16p + (((size_t)img * 8 + ck) * PH + h_lo) * (PW * 32);
        gload16(sg + (size_t)tid * 8, &slab[0] + (size_t)tid * 8);
        gload16(sg + (size_t)(tid + 512) * 8, &slab[0] + (size_t)(tid + 512) * 8);
        if (tid < 488)
            gload16(sg + (size_t)(tid + 1024) * 8, &slab[0] + (size_t)(tid + 1024) * 8);
#pragma unroll
        for (int tap = 0; tap < 9; ++tap) {
            int g = ck * 9 + tap;
            // wait own stage(s) done, then block-wide rendezvous
            asm volatile("s_waitcnt vmcnt(0)\n\ts_barrier" ::: "memory");
            __builtin_amdgcn_sched_barrier(0);
            // prefetch A(g+1) (safe: all waves finished compute(g-1) -> buffer free)
            if (g < 71) {
                int nt = g + 1, tapn = nt % 9, ckn = nt / 9;
                const f16* wA = w16 + ((size_t)(tapn * 8 + ckn) * 512 + co0) * 32;
                f16* dst = &At[nt & 1][0];
                gload16(wA + (size_t)tid * 8, dst + (size_t)tid * 8);
                gload16(wA + (size_t)(tid + 512) * 8, dst + (size_t)(tid + 512) * 8);
            }
            // compute tap on At[g&1] + slab
            int dh = tap / 3 - 1, dw = tap % 3 - 1;
            int tapadd = (dh * PW + dw) * 64;
            const f16* Ab = &At[g & 1][0];
            f16x8 af[8];
#pragma unroll
            for (int mf = 0; mf < 8; ++mf)
                af[mf] = *(const f16x8*)(Ab + ((wm * 128 + mf * 16 + l15) * 32 + kg * 8));
            f16x8 bf[3];
#pragma unroll
            for (int nf = 0; nf < 3; ++nf)
                bf[nf] = *(const f16x8*)((const char*)slab + (roff[nf] + tapadd));
            __builtin_amdgcn_s_setprio(1);
#pragma unroll
            for (int nf = 0; nf < 3; ++nf)
#pragma unroll
                for (int mf = 0; mf < 8; ++mf)
                    acc[mf][nf] = __builtin_amdgcn_mfma_f32_16x16x32_f16(
                        af[mf], bf[nf], acc[mf][nf], 0, 0, 0);
            __builtin_amdgcn_s_setprio(0);
        }
    }
    // epilogue: BN + leaky -> y16
#pragma unroll
    for (int mf = 0; mf < 8; ++mf) {
        int cob = co0 + wm * 128 + mf * 16 + kg * 4;
        f32x4 sc = *(const f32x4*)(bnscale + cob);
        f32x4 sh = *(const f32x4*)(bnshift + cob);
#pragma unroll
        for (int nf = 0; nf < 3; ++nf) {
            if (!vn[nf]) continue;
            f16x4 o;
#pragma unroll
            for (int i = 0; i < 4; ++i) {
                float v = acc[mf][nf][i] * sc[i] + sh[i];
                o[i] = (f16)(v > 0.f ? v : 0.1f * v);
            }
            *(f16x4*)(y16 + ((size_t)img * GG + nlist[nf]) * CMID + cob) = o;
        }
    }
}

// ---- conv2 (1x1, K=512) + bias + YOLO decode. 256 thr / 4 waves, 128 n per block ----
__global__ __launch_bounds__(256) void k_conv2(
    const f16* __restrict__ y16, const f16* __restrict__ w2_16,
    const float* __restrict__ b2, float* __restrict__ out) {
    __shared__ float ct[128][81];   // 41472 B
    int img = blockIdx.x / 22, nb = blockIdx.x % 22;
    int n0 = nb * 128;
    int tid = threadIdx.x;
    int lane = tid & 63, wave = tid >> 6;
    int l15 = lane & 15, kg = lane >> 4;

    f32x4 acc[5][2];
#pragma unroll
    for (int a = 0; a < 5; ++a)
#pragma unroll
        for (int b = 0; b < 2; ++b) {
            acc[a][b][0] = 0.f; acc[a][b][1] = 0.f;
            acc[a][b][2] = 0.f; acc[a][b][3] = 0.f;
        }

    const f16* yb = y16 + (size_t)img * GG * CMID;
    int nn[2];
#pragma unroll
    for (int nf = 0; nf < 2; ++nf) {
        int n = n0 + wave * 32 + nf * 16 + l15;
        nn[nf] = n < GG ? n : GG - 1;
    }
    for (int c0 = 0; c0 < CMID; c0 += 32) {
        f16x8 af[5];
#pragma unroll
        for (int mf = 0; mf < 5; ++mf) {
            int co = mf * 16 + l15;
            if (co < COUT)
                af[mf] = *(const f16x8*)(w2_16 + (size_t)co * CMID + c0 + kg * 8);
            else {
#pragma unroll
                for (int k = 0; k < 8; ++k) af[mf][k] = (f16)0;
            }
        }
#pragma unroll
        for (int nf = 0; nf < 2; ++nf) {
            f16x8 bf = *(const f16x8*)(yb + (size_t)nn[nf] * CMID + c0 + kg * 8);
#pragma unroll
            for (int mf = 0; mf < 5; ++mf)
                acc[mf][nf] = __builtin_amdgcn_mfma_f32_16x16x32_f16(
                    af[mf], bf, acc[mf][nf], 0, 0, 0);
        }
    }
#pragma unroll
    for (int mf = 0; mf < 5; ++mf)
#pragma unroll
        for (int nf = 0; nf < 2; ++nf)
            *(f32x4*)(&ct[wave * 32 + nf * 16 + l15][mf * 16 + kg * 4]) = acc[mf][nf];
    __syncthreads();
    // decode: 384 (anchor, n) items over 256 threads
    for (int j = tid; j < 384; j += 256) {
        int a = j >> 7, nl = j & 127;
        int n = n0 + nl;
        if (n >= GG) continue;
        const float* t = &ct[nl][a * 25];
        float tv[25];
#pragma unroll
        for (int q = 0; q < 25; ++q) tv[q] = t[q] + b2[a * 25 + q];
        int h = n / GDIM, w = n % GDIM;
        const float AW[3] = {10.f, 16.f, 33.f};
        const float AH[3] = {13.f, 30.f, 23.f};
        float bx = (sigmoidf_(tv[0]) + (float)w) * 8.0f;
        float by = (sigmoidf_(tv[1]) + (float)h) * 8.0f;
        float bw_ = __expf(tv[2]) * AW[a];
        float bh_ = __expf(tv[3]) * AH[a];
        float* o = out + ((size_t)img * 8112 + (size_t)a * GG + n) * 25;
        o[0] = bx; o[1] = by; o[2] = bw_; o[3] = bh_;
        o[4] = sigmoidf_(tv[4]);
#pragma unroll
        for (int q = 0; q < 20; ++q) o[5 + q] = sigmoidf_(tv[5 + q]);
    }
}

extern "C" void kernel_launch(void* const* d_in, const int* in_sizes, int n_in,
                              void* d_out, int out_size, void* d_ws, size_t ws_size,
                              hipStream_t stream) {
    (void)in_sizes; (void)n_in; (void)out_size; (void)ws_size;
    const float* x     = (const float*)d_in[0];
    const float* w1    = (const float*)d_in[1];
    const float* gamma = (const float*)d_in[2];
    const float* beta  = (const float*)d_in[3];
    const float* mean  = (const float*)d_in[4];
    const float* var   = (const float*)d_in[5];
    const float* w2    = (const float*)d_in[6];
    const float* b2    = (const float*)d_in[7];
    float* out = (float*)d_out;

    char* ws = (char*)d_ws;
    // x16p: 16*8*60*54*32*2 = 26,542,080 B
    f16* x16p     = (f16*)(ws);
    f16* w16      = (f16*)(ws + 26542080);     // 2,359,296 B
    f16* w2_16    = (f16*)(ws + 28901376);     //    76,800 B
    float* bnscale = (float*)(ws + 28978176);  //     2,048 B
    float* bnshift = (float*)(ws + 28980224);  //     2,048 B
    f16* y16      = (f16*)(ws + 28982272);     // 44,302,336 B (total ~73.3 MB)

    hipMemsetAsync(x16p, 0, 26542080, stream);
    k_prep_x<<<dim3(22, 8, NIMG), 256, 0, stream>>>(x, x16p);
    k_prep_w<<<4608, 256, 0, stream>>>(w1, w2, gamma, beta, mean, var,
                                       w16, w2_16, bnscale, bnshift);
    k_conv1<<<dim3(NIMG * NSPB, 2), 512, 0, stream>>>(x16p, w16, bnscale,
                                                      bnshift, y16);
    k_conv2<<<NIMG * 22, 256, 0, stream>>>(y16, w2_16, b2, out);
}

// Round 3
// 163.736 us; speedup vs baseline: 1.6930x; 1.3014x over previous
//
#include <hip/hip_runtime.h>

typedef _Float16 f16;
typedef _Float16 f16x8 __attribute__((ext_vector_type(8)));
typedef _Float16 f16x4 __attribute__((ext_vector_type(4)));
typedef float f32x4 __attribute__((ext_vector_type(4)));

#define GDIM 52
#define GG 2704          // 52*52
#define CIN 256
#define CMID 512
#define COUT 75
#define NIMG 16
#define SPT 192          // conv1 spatial tile
#define NSPB 15          // ceil(2704/192)
#define PH 60            // padded rows in x16p
#define PW 54            // padded cols

__device__ __forceinline__ float sigmoidf_(float x) {
    return 1.0f / (1.0f + __expf(-x));
}

__device__ __forceinline__ void gload16(const void* g, void* l) {
    __builtin_amdgcn_global_load_lds(
        (const __attribute__((address_space(1))) unsigned int*)g,
        (__attribute__((address_space(3))) unsigned int*)l, 16, 0, 0);
}

// ---- prep: x [img][ci][hw] f32 -> x16p [img][ck][h+1][w+1][32ci] f16 (padded) ----
__global__ __launch_bounds__(256) void k_prep_x(const float* __restrict__ x,
                                                f16* __restrict__ x16p) {
    __shared__ float ls[32][133];
    int hw0 = blockIdx.x * 128, ck = blockIdx.y, img = blockIdx.z;
    int tid = threadIdx.x;
    const float* xb = x + ((size_t)img * CIN + ck * 32) * GG;
#pragma unroll
    for (int i = 0; i < 16; ++i) {
        int idx = tid + i * 256;
        int r = idx >> 7, c = idx & 127;
        int hw = hw0 + c;
        ls[r][c] = (hw < GG) ? xb[(size_t)r * GG + hw] : 0.0f;
    }
    __syncthreads();
    int col = tid >> 1, half = tid & 1;
    int hw = hw0 + col;
    if (hw < GG) {
        int h = hw / GDIM, w = hw % GDIM;
        f16* dst = x16p + ((((size_t)img * 8 + ck) * PH + h + 1) * PW + (w + 1)) * 32 + half * 16;
        f16x8 o0, o1;
#pragma unroll
        for (int j = 0; j < 8; ++j) o0[j] = (f16)ls[half * 16 + j][col];
#pragma unroll
        for (int j = 0; j < 8; ++j) o1[j] = (f16)ls[half * 16 + 8 + j][col];
        *(f16x8*)dst = o0;
        *(f16x8*)(dst + 8) = o1;
    }
}

// ---- prep: weights + BN fold.  w16 layout [tap][ck][co][32ci] ----
__global__ __launch_bounds__(256) void k_prep_w(
    const float* __restrict__ w1, const float* __restrict__ w2,
    const float* __restrict__ gamma, const float* __restrict__ beta,
    const float* __restrict__ mean, const float* __restrict__ var,
    f16* __restrict__ w16, f16* __restrict__ w2_16,
    float* __restrict__ bnscale, float* __restrict__ bnshift) {
    int i = blockIdx.x * 256 + threadIdx.x;   // exactly 9*8*512*32 = 1,179,648 threads
    int cl = i & 31;
    int co = (i >> 5) & 511;
    int ckt = i >> 14;          // tap*8 + ck
    int ck = ckt & 7, tap = ckt >> 3;
    int ci = ck * 32 + cl;
    w16[i] = (f16)w1[(size_t)co * 2304 + ci * 9 + tap];
    if (i < COUT * CMID) w2_16[i] = (f16)w2[i];
    if (i < CMID) {
        float s = gamma[i] * rsqrtf(var[i] + 1e-5f);
        bnscale[i] = s;
        bnshift[i] = beta[i] - mean[i] * s;
    }
}

// ---- conv1: 3x3 + BN + LeakyReLU -> y16 [img][n][co] ----
// 512 thr / 8 waves (4 wm x 2 wn); block 256co x 192sp; wave 64co x 96sp.
// Pipelined: A triple-buffer (1 tap ahead), slab double-buffer (issued tap 4),
// counted vmcnt (never 0 in main loop), one s_barrier per tap.
__global__ __launch_bounds__(512, 2) void k_conv1(
    const f16* __restrict__ x16p, const f16* __restrict__ w16,
    const float* __restrict__ bnscale, const float* __restrict__ bnshift,
    f16* __restrict__ y16) {
    __shared__ __align__(16) f16 At[3][8192];     // 3 x 16 KB  (256co x 32ci)
    __shared__ __align__(16) f16 slab[2][12288];  // 2 x 24 KB  (7x54 rows used)
    int img = blockIdx.x / NSPB, sb = blockIdx.x % NSPB;
    int n0 = sb * SPT;
    int h_lo = n0 / GDIM;
    int co0 = blockIdx.y * 256;
    int tid = threadIdx.x;
    int lane = tid & 63, wave = tid >> 6;
    int wm = wave >> 1, wn = wave & 1;
    int l15 = lane & 15, kg = lane >> 4;

    int roff[6];
#pragma unroll
    for (int nf = 0; nf < 6; ++nf) {
        int n = n0 + wn * 96 + nf * 16 + l15;
        int nc = n < GG ? n : GG - 1;
        int hh = nc / GDIM, ww = nc % GDIM;
        roff[nf] = ((hh - h_lo + 1) * PW + (ww + 1)) * 64 + kg * 16;  // byte off
    }

    f32x4 acc[4][6];
#pragma unroll
    for (int a = 0; a < 4; ++a)
#pragma unroll
        for (int b = 0; b < 6; ++b) {
            acc[a][b][0] = 0.f; acc[a][b][1] = 0.f;
            acc[a][b][2] = 0.f; acc[a][b][3] = 0.f;
        }

    const f16* xbase = x16p + ((size_t)img * 8 * PH + h_lo) * (PW * 32);

    // prologue: stage A(0) and slab(0)
    {
        const f16* wA = w16 + (size_t)co0 * 32;   // tap0, ck0
        gload16(wA + (size_t)tid * 8, &At[0][0] + (size_t)tid * 8);
        gload16(wA + (size_t)(tid + 512) * 8, &At[0][0] + (size_t)(tid + 512) * 8);
        const f16* sg = xbase;                    // ck0
        gload16(sg + (size_t)tid * 8, &slab[0][0] + (size_t)tid * 8);
        gload16(sg + (size_t)(tid + 512) * 8, &slab[0][0] + (size_t)(tid + 512) * 8);
        gload16(sg + (size_t)(tid + 1024) * 8, &slab[0][0] + (size_t)(tid + 1024) * 8);
    }

    for (int ck = 0; ck < 8; ++ck) {
        const char* Sb = (const char*)&slab[ck & 1][0];
#pragma unroll
        for (int tap = 0; tap < 9; ++tap) {
            // ---- issue prefetches (buffers free by triple/double buffering) ----
            if (tap == 4 && ck < 7) {   // slab(ck+1), needed 5 taps from now
                const f16* sg = xbase + (size_t)(ck + 1) * (PH * PW * 32);
                f16* sd = &slab[(ck + 1) & 1][0];
                gload16(sg + (size_t)tid * 8, sd + (size_t)tid * 8);
                gload16(sg + (size_t)(tid + 512) * 8, sd + (size_t)(tid + 512) * 8);
                gload16(sg + (size_t)(tid + 1024) * 8, sd + (size_t)(tid + 1024) * 8);
            }
            if (!(ck == 7 && tap == 8)) {  // A(g+1)
                const int tapn = (tap + 1) % 9;            // compile-time
                const int ckn = ck + (tap == 8 ? 1 : 0);
                const f16* wA = w16 + ((size_t)(tapn * 8 + ckn) * 512 + co0) * 32;
                f16* dst = &At[(tap + 1) % 3][0];          // compile-time index
                gload16(wA + (size_t)tid * 8, dst + (size_t)tid * 8);
                gload16(wA + (size_t)(tid + 512) * 8, dst + (size_t)(tid + 512) * 8);
            }
            // ---- counted wait: force A(g) [+slab(ck) via ordering], keep newest ----
            if (ck == 7 && tap == 8)
                asm volatile("s_waitcnt vmcnt(0)" ::: "memory");
            else if (tap == 4 && ck < 7)
                asm volatile("s_waitcnt vmcnt(5)" ::: "memory");
            else
                asm volatile("s_waitcnt vmcnt(2)" ::: "memory");
            __builtin_amdgcn_s_barrier();
            __builtin_amdgcn_sched_barrier(0);
            // ---- fragments ----
            const f16* Ab = &At[tap % 3][0];
            const int dh = tap / 3 - 1, dw = tap % 3 - 1;
            const int tapadd = (dh * PW + dw) * 64;
            f16x8 af[4], bf[6];
#pragma unroll
            for (int mf = 0; mf < 4; ++mf)
                af[mf] = *(const f16x8*)(Ab + ((wm * 64 + mf * 16 + l15) * 32 + kg * 8));
#pragma unroll
            for (int nf = 0; nf < 6; ++nf)
                bf[nf] = *(const f16x8*)(Sb + (roff[nf] + tapadd));
            __builtin_amdgcn_s_setprio(1);
#pragma unroll
            for (int nf = 0; nf < 6; ++nf)
#pragma unroll
                for (int mf = 0; mf < 4; ++mf)
                    acc[mf][nf] = __builtin_amdgcn_mfma_f32_16x16x32_f16(
                        af[mf], bf[nf], acc[mf][nf], 0, 0, 0);
            __builtin_amdgcn_s_setprio(0);
            __builtin_amdgcn_sched_barrier(0);
        }
    }
    // epilogue: BN + leaky -> y16
#pragma unroll
    for (int mf = 0; mf < 4; ++mf) {
        int cob = co0 + wm * 64 + mf * 16 + kg * 4;
        f32x4 sc = *(const f32x4*)(bnscale + cob);
        f32x4 sh = *(const f32x4*)(bnshift + cob);
#pragma unroll
        for (int nf = 0; nf < 6; ++nf) {
            int n = n0 + wn * 96 + nf * 16 + l15;
            if (n >= GG) continue;
            f16x4 o;
#pragma unroll
            for (int i = 0; i < 4; ++i) {
                float v = acc[mf][nf][i] * sc[i] + sh[i];
                o[i] = (f16)(v > 0.f ? v : 0.1f * v);
            }
            *(f16x4*)(y16 + ((size_t)img * GG + n) * CMID + cob) = o;
        }
    }
}

// ---- conv2 (1x1, K=512) + bias + YOLO decode. 256 thr / 4 waves, 128 n per block ----
__global__ __launch_bounds__(256) void k_conv2(
    const f16* __restrict__ y16, const f16* __restrict__ w2_16,
    const float* __restrict__ b2, float* __restrict__ out) {
    __shared__ float ct[128][81];   // 41472 B
    int img = blockIdx.x / 22, nb = blockIdx.x % 22;
    int n0 = nb * 128;
    int tid = threadIdx.x;
    int lane = tid & 63, wave = tid >> 6;
    int l15 = lane & 15, kg = lane >> 4;

    f32x4 acc[5][2];
#pragma unroll
    for (int a = 0; a < 5; ++a)
#pragma unroll
        for (int b = 0; b < 2; ++b) {
            acc[a][b][0] = 0.f; acc[a][b][1] = 0.f;
            acc[a][b][2] = 0.f; acc[a][b][3] = 0.f;
        }

    const f16* yb = y16 + (size_t)img * GG * CMID;
    int nn[2];
#pragma unroll
    for (int nf = 0; nf < 2; ++nf) {
        int n = n0 + wave * 32 + nf * 16 + l15;
        nn[nf] = n < GG ? n : GG - 1;
    }
    for (int c0 = 0; c0 < CMID; c0 += 32) {
        f16x8 af[5];
#pragma unroll
        for (int mf = 0; mf < 5; ++mf) {
            int co = mf * 16 + l15;
            if (co < COUT)
                af[mf] = *(const f16x8*)(w2_16 + (size_t)co * CMID + c0 + kg * 8);
            else {
#pragma unroll
                for (int k = 0; k < 8; ++k) af[mf][k] = (f16)0;
            }
        }
#pragma unroll
        for (int nf = 0; nf < 2; ++nf) {
            f16x8 bf = *(const f16x8*)(yb + (size_t)nn[nf] * CMID + c0 + kg * 8);
#pragma unroll
            for (int mf = 0; mf < 5; ++mf)
                acc[mf][nf] = __builtin_amdgcn_mfma_f32_16x16x32_f16(
                    af[mf], bf, acc[mf][nf], 0, 0, 0);
        }
    }
#pragma unroll
    for (int mf = 0; mf < 5; ++mf)
#pragma unroll
        for (int nf = 0; nf < 2; ++nf)
            *(f32x4*)(&ct[wave * 32 + nf * 16 + l15][mf * 16 + kg * 4]) = acc[mf][nf];
    __syncthreads();
    // decode: 384 (anchor, n) items over 256 threads
    for (int j = tid; j < 384; j += 256) {
        int a = j >> 7, nl = j & 127;
        int n = n0 + nl;
        if (n >= GG) continue;
        const float* t = &ct[nl][a * 25];
        float tv[25];
#pragma unroll
        for (int q = 0; q < 25; ++q) tv[q] = t[q] + b2[a * 25 + q];
        int h = n / GDIM, w = n % GDIM;
        const float AW[3] = {10.f, 16.f, 33.f};
        const float AH[3] = {13.f, 30.f, 23.f};
        float bx = (sigmoidf_(tv[0]) + (float)w) * 8.0f;
        float by = (sigmoidf_(tv[1]) + (float)h) * 8.0f;
        float bw_ = __expf(tv[2]) * AW[a];
        float bh_ = __expf(tv[3]) * AH[a];
        float* o = out + ((size_t)img * 8112 + (size_t)a * GG + n) * 25;
        o[0] = bx; o[1] = by; o[2] = bw_; o[3] = bh_;
        o[4] = sigmoidf_(tv[4]);
#pragma unroll
        for (int q = 0; q < 20; ++q) o[5 + q] = sigmoidf_(tv[5 + q]);
    }
}

extern "C" void kernel_launch(void* const* d_in, const int* in_sizes, int n_in,
                              void* d_out, int out_size, void* d_ws, size_t ws_size,
                              hipStream_t stream) {
    (void)in_sizes; (void)n_in; (void)out_size; (void)ws_size;
    const float* x     = (const float*)d_in[0];
    const float* w1    = (const float*)d_in[1];
    const float* gamma = (const float*)d_in[2];
    const float* beta  = (const float*)d_in[3];
    const float* mean  = (const float*)d_in[4];
    const float* var   = (const float*)d_in[5];
    const float* w2    = (const float*)d_in[6];
    const float* b2    = (const float*)d_in[7];
    float* out = (float*)d_out;

    char* ws = (char*)d_ws;
    // x16p: 16*8*60*54*32*2 = 26,542,080 B (+8 KB slack for staging over-read)
    f16* x16p     = (f16*)(ws);
    f16* w16      = (f16*)(ws + 26550272);     // 2,359,296 B
    f16* w2_16    = (f16*)(ws + 28909568);     //    76,800 B
    float* bnscale = (float*)(ws + 28986368);  //     2,048 B
    float* bnshift = (float*)(ws + 28988416);  //     2,048 B
    f16* y16      = (f16*)(ws + 28990464);     // 44,302,336 B (total ~73.3 MB)

    hipMemsetAsync(x16p, 0, 26542080, stream);
    k_prep_x<<<dim3(22, 8, NIMG), 256, 0, stream>>>(x, x16p);
    k_prep_w<<<4608, 256, 0, stream>>>(w1, w2, gamma, beta, mean, var,
                                       w16, w2_16, bnscale, bnshift);
    k_conv1<<<dim3(NIMG * NSPB, 2), 512, 0, stream>>>(x16p, w16, bnscale,
                                                      bnshift, y16);
    k_conv2<<<NIMG * 22, 256, 0, stream>>>(y16, w2_16, b2, out);
}

// Round 4
// 155.380 us; speedup vs baseline: 1.7841x; 1.0538x over previous
//
#include <hip/hip_runtime.h>

typedef _Float16 f16;
typedef _Float16 f16x8 __attribute__((ext_vector_type(8)));
typedef _Float16 f16x4 __attribute__((ext_vector_type(4)));
typedef float f32x4 __attribute__((ext_vector_type(4)));

#define GDIM 52
#define GG 2704          // 52*52
#define CIN 256
#define CMID 512
#define COUT 75
#define NIMG 16
#define SPT 192          // conv1 spatial tile
#define NSPB 15          // ceil(2704/192)
#define PH 60            // padded rows in x16p
#define PW 54            // padded cols

// LDS map (bytes): At[3] @ 0 (3 x 16384), slab[2] @ 49152 (2 x 32768) = 114688
#define AT_OFF 0
#define AT_SZ 16384
#define SLAB_OFF 49152
#define SLAB_SZ 32768

__device__ __forceinline__ float sigmoidf_(float x) {
    return 1.0f / (1.0f + __expf(-x));
}

__device__ __forceinline__ void gload16(const void* g, void* l) {
    __builtin_amdgcn_global_load_lds(
        (const __attribute__((address_space(1))) unsigned int*)g,
        (__attribute__((address_space(3))) unsigned int*)l, 16, 0, 0);
}

// ---- prep: x [img][ci][hw] f32 -> x16p [img][ck][h+1][w+1][32ci] f16 (padded) ----
__global__ __launch_bounds__(256) void k_prep_x(const float* __restrict__ x,
                                                f16* __restrict__ x16p) {
    __shared__ float ls[32][133];
    int hw0 = blockIdx.x * 128, ck = blockIdx.y, img = blockIdx.z;
    int tid = threadIdx.x;
    const float* xb = x + ((size_t)img * CIN + ck * 32) * GG;
#pragma unroll
    for (int i = 0; i < 16; ++i) {
        int idx = tid + i * 256;
        int r = idx >> 7, c = idx & 127;
        int hw = hw0 + c;
        ls[r][c] = (hw < GG) ? xb[(size_t)r * GG + hw] : 0.0f;
    }
    __syncthreads();
    int col = tid >> 1, half = tid & 1;
    int hw = hw0 + col;
    if (hw < GG) {
        int h = hw / GDIM, w = hw % GDIM;
        f16* dst = x16p + ((((size_t)img * 8 + ck) * PH + h + 1) * PW + (w + 1)) * 32 + half * 16;
        f16x8 o0, o1;
#pragma unroll
        for (int j = 0; j < 8; ++j) o0[j] = (f16)ls[half * 16 + j][col];
#pragma unroll
        for (int j = 0; j < 8; ++j) o1[j] = (f16)ls[half * 16 + 8 + j][col];
        *(f16x8*)dst = o0;
        *(f16x8*)(dst + 8) = o1;
    }
}

// ---- prep: weights + BN fold.  w16 layout [tap][ck][co][32ci] ----
__global__ __launch_bounds__(256) void k_prep_w(
    const float* __restrict__ w1, const float* __restrict__ w2,
    const float* __restrict__ gamma, const float* __restrict__ beta,
    const float* __restrict__ mean, const float* __restrict__ var,
    f16* __restrict__ w16, f16* __restrict__ w2_16,
    float* __restrict__ bnscale, float* __restrict__ bnshift) {
    int i = blockIdx.x * 256 + threadIdx.x;   // exactly 9*8*512*32 = 1,179,648 threads
    int cl = i & 31;
    int co = (i >> 5) & 511;
    int ckt = i >> 14;          // tap*8 + ck
    int ck = ckt & 7, tap = ckt >> 3;
    int ci = ck * 32 + cl;
    w16[i] = (f16)w1[(size_t)co * 2304 + ci * 9 + tap];
    if (i < COUT * CMID) w2_16[i] = (f16)w2[i];
    if (i < CMID) {
        float s = gamma[i] * rsqrtf(var[i] + 1e-5f);
        bnscale[i] = s;
        bnshift[i] = beta[i] - mean[i] * s;
    }
}

// ---- conv1: 3x3 + BN + LeakyReLU -> y16 [half][img][n][256co] ----
// 512 thr / 8 waves (4 wm x 2 wn); block 256co x 192sp; wave 64co x 96sp.
// LDS layouts slot-transposed: At = [s][256co][16B], slab = [s][512pix][16B]
// (frag reads 16-lane-contiguous -> conflict-free; staging = bit-swap source).
__global__ __launch_bounds__(512, 2) void k_conv1(
    const f16* __restrict__ x16p, const f16* __restrict__ w16,
    const float* __restrict__ bnscale, const float* __restrict__ bnshift,
    f16* __restrict__ y16) {
    __shared__ __align__(16) char smem[114688];
    int img = blockIdx.x / NSPB, sb = blockIdx.x % NSPB;
    int n0 = sb * SPT;
    int h_lo = n0 / GDIM;
    int half = blockIdx.y;
    int co0 = half * 256;
    int tid = threadIdx.x;
    int lane = tid & 63, wave = tid >> 6;
    int wm = wave >> 1, wn = wave & 1;
    int l15 = lane & 15, kg = lane >> 4;

    int roff[6];   // pix*8 (f16 units)
#pragma unroll
    for (int nf = 0; nf < 6; ++nf) {
        int n = n0 + wn * 96 + nf * 16 + l15;
        int nc = n < GG ? n : GG - 1;
        int hh = nc / GDIM, ww = nc % GDIM;
        roff[nf] = ((hh - h_lo + 1) * PW + (ww + 1)) * 8;
    }

    f32x4 acc[4][6];
#pragma unroll
    for (int a = 0; a < 4; ++a)
#pragma unroll
        for (int b = 0; b < 6; ++b) {
            acc[a][b][0] = 0.f; acc[a][b][1] = 0.f;
            acc[a][b][2] = 0.f; acc[a][b][3] = 0.f;
        }

    const f16* xbase = x16p + ((size_t)img * 8 * PH + h_lo) * (PW * 32);
    int spix = tid < 378 ? tid : 377;   // clamped slab pixel (uniform DMA count)

    // prologue: A(0) then slab(0)
    {
        const f16* wA = w16 + (size_t)co0 * 32;   // tap0, ck0
        f16* dst = (f16*)(smem + AT_OFF);
#pragma unroll
        for (int p = 0; p < 2; ++p) {
            int u = p * 512 + tid, s = u >> 8, c = u & 255;
            gload16(wA + (size_t)c * 32 + s * 8, dst + (size_t)u * 8);
        }
        f16* sd = (f16*)(smem + SLAB_OFF);
#pragma unroll
        for (int p = 0; p < 4; ++p)
            gload16(xbase + (size_t)spix * 32 + p * 8, sd + ((size_t)p * 512 + tid) * 8);
    }

    for (int ck = 0; ck < 8; ++ck) {
#pragma unroll
        for (int tap = 0; tap < 9; ++tap) {
            // ---- issue prefetches: A(g+1) first, then slab(ck+1) at tap 4 ----
            if (!(ck == 7 && tap == 8)) {
                const int tapn = (tap + 1) % 9;
                const int ckn = ck + (tap == 8 ? 1 : 0);
                const f16* wA = w16 + ((size_t)(tapn * 8 + ckn) * 512 + co0) * 32;
                f16* dst = (f16*)(smem + AT_OFF + ((tap + 1) % 3) * AT_SZ);
#pragma unroll
                for (int p = 0; p < 2; ++p) {
                    int u = p * 512 + tid, s = u >> 8, c = u & 255;
                    gload16(wA + (size_t)c * 32 + s * 8, dst + (size_t)u * 8);
                }
            }
            if (tap == 4 && ck < 7) {
                const f16* sg = xbase + (size_t)(ck + 1) * (PH * PW * 32);
                f16* sd = (f16*)(smem + SLAB_OFF + ((ck + 1) & 1) * SLAB_SZ);
#pragma unroll
                for (int p = 0; p < 4; ++p)
                    gload16(sg + (size_t)spix * 32 + p * 8, sd + ((size_t)p * 512 + tid) * 8);
            }
            // ---- counted waits (per-wave ledger; uniform issue counts) ----
            if (ck == 7 && tap == 8)
                asm volatile("s_waitcnt vmcnt(0)" ::: "memory");
            else if ((tap == 4 || tap == 5) && ck < 7)
                asm volatile("s_waitcnt vmcnt(6)" ::: "memory");
            else
                asm volatile("s_waitcnt vmcnt(2)" ::: "memory");
            __builtin_amdgcn_s_barrier();
            __builtin_amdgcn_sched_barrier(0);
            // ---- fragments (conflict-free contiguous reads) ----
            const f16* Ab = (const f16*)(smem + AT_OFF + (tap % 3) * AT_SZ);
            const f16* Sb = (const f16*)(smem + SLAB_OFF + (ck & 1) * SLAB_SZ);
            const int tappix = (tap / 3 - 1) * PW + (tap % 3 - 1);
            f16x8 af[4], bf[6];
#pragma unroll
            for (int mf = 0; mf < 4; ++mf)
                af[mf] = *(const f16x8*)(Ab + kg * 2048 + (wm * 64 + l15) * 8 + mf * 128);
#pragma unroll
            for (int nf = 0; nf < 6; ++nf)
                bf[nf] = *(const f16x8*)(Sb + kg * 4096 + roff[nf] + tappix * 8);
            __builtin_amdgcn_s_setprio(1);
#pragma unroll
            for (int nf = 0; nf < 6; ++nf)
#pragma unroll
                for (int mf = 0; mf < 4; ++mf)
                    acc[mf][nf] = __builtin_amdgcn_mfma_f32_16x16x32_f16(
                        af[mf], bf[nf], acc[mf][nf], 0, 0, 0);
            __builtin_amdgcn_s_setprio(0);
            __builtin_amdgcn_sched_barrier(0);
        }
    }
    // ---- epilogue: BN + leaky -> LDS transpose (stride 264 f16) -> linear copy ----
    __syncthreads();
    f16* tb = (f16*)smem;
#pragma unroll
    for (int mf = 0; mf < 4; ++mf) {
        int cr = wm * 64 + mf * 16 + kg * 4;
        f32x4 sc = *(const f32x4*)(bnscale + co0 + cr);
        f32x4 sh = *(const f32x4*)(bnshift + co0 + cr);
#pragma unroll
        for (int nf = 0; nf < 6; ++nf) {
            int pl = wn * 96 + nf * 16 + l15;
            f16x4 o;
#pragma unroll
            for (int i = 0; i < 4; ++i) {
                float v = acc[mf][nf][i] * sc[i] + sh[i];
                o[i] = (f16)(v > 0.f ? v : 0.1f * v);
            }
            *(f16x4*)(tb + pl * 264 + cr) = o;
        }
    }
    __syncthreads();
    int valid = GG - n0; if (valid > SPT) valid = SPT;
    f16* yb = y16 + (size_t)half * (NIMG * (size_t)GG * 256) + ((size_t)img * GG + n0) * 256;
#pragma unroll
    for (int p = 0; p < 12; ++p) {
        int u = p * 512 + tid, pl = u >> 5, slot = u & 31;
        if (pl < valid)
            *(f16x8*)(yb + (size_t)pl * 256 + slot * 8) =
                *(const f16x8*)(tb + pl * 264 + slot * 8);
    }
}

// ---- conv2 (1x1, K=512) + bias + YOLO decode. 256 thr / 4 waves, 128 n per block ----
__global__ __launch_bounds__(256) void k_conv2(
    const f16* __restrict__ y16, const f16* __restrict__ w2_16,
    const float* __restrict__ b2, float* __restrict__ out) {
    __shared__ float ct[128][81];   // 41472 B
    int img = blockIdx.x / 22, nb = blockIdx.x % 22;
    int n0 = nb * 128;
    int tid = threadIdx.x;
    int lane = tid & 63, wave = tid >> 6;
    int l15 = lane & 15, kg = lane >> 4;

    f32x4 acc[5][2];
#pragma unroll
    for (int a = 0; a < 5; ++a)
#pragma unroll
        for (int b = 0; b < 2; ++b) {
            acc[a][b][0] = 0.f; acc[a][b][1] = 0.f;
            acc[a][b][2] = 0.f; acc[a][b][3] = 0.f;
        }

    int nn[2];
#pragma unroll
    for (int nf = 0; nf < 2; ++nf) {
        int n = n0 + wave * 32 + nf * 16 + l15;
        nn[nf] = n < GG ? n : GG - 1;
    }
    for (int c0 = 0; c0 < CMID; c0 += 32) {
        const f16* yb = y16 + (size_t)(c0 >> 8) * (NIMG * (size_t)GG * 256) +
                        (size_t)img * GG * 256;
        int c = c0 & 255;
        f16x8 af[5];
#pragma unroll
        for (int mf = 0; mf < 5; ++mf) {
            int co = mf * 16 + l15;
            if (co < COUT)
                af[mf] = *(const f16x8*)(w2_16 + (size_t)co * CMID + c0 + kg * 8);
            else {
#pragma unroll
                for (int k = 0; k < 8; ++k) af[mf][k] = (f16)0;
            }
        }
#pragma unroll
        for (int nf = 0; nf < 2; ++nf) {
            f16x8 bf = *(const f16x8*)(yb + (size_t)nn[nf] * 256 + c + kg * 8);
#pragma unroll
            for (int mf = 0; mf < 5; ++mf)
                acc[mf][nf] = __builtin_amdgcn_mfma_f32_16x16x32_f16(
                    af[mf], bf, acc[mf][nf], 0, 0, 0);
        }
    }
#pragma unroll
    for (int mf = 0; mf < 5; ++mf)
#pragma unroll
        for (int nf = 0; nf < 2; ++nf)
            *(f32x4*)(&ct[wave * 32 + nf * 16 + l15][mf * 16 + kg * 4]) = acc[mf][nf];
    __syncthreads();
    // decode: 384 (anchor, n) items over 256 threads
    for (int j = tid; j < 384; j += 256) {
        int a = j >> 7, nl = j & 127;
        int n = n0 + nl;
        if (n >= GG) continue;
        const float* t = &ct[nl][a * 25];
        float tv[25];
#pragma unroll
        for (int q = 0; q < 25; ++q) tv[q] = t[q] + b2[a * 25 + q];
        int h = n / GDIM, w = n % GDIM;
        const float AW[3] = {10.f, 16.f, 33.f};
        const float AH[3] = {13.f, 30.f, 23.f};
        float bx = (sigmoidf_(tv[0]) + (float)w) * 8.0f;
        float by = (sigmoidf_(tv[1]) + (float)h) * 8.0f;
        float bw_ = __expf(tv[2]) * AW[a];
        float bh_ = __expf(tv[3]) * AH[a];
        float* o = out + ((size_t)img * 8112 + (size_t)a * GG + n) * 25;
        o[0] = bx; o[1] = by; o[2] = bw_; o[3] = bh_;
        o[4] = sigmoidf_(tv[4]);
#pragma unroll
        for (int q = 0; q < 20; ++q) o[5 + q] = sigmoidf_(tv[5 + q]);
    }
}

extern "C" void kernel_launch(void* const* d_in, const int* in_sizes, int n_in,
                              void* d_out, int out_size, void* d_ws, size_t ws_size,
                              hipStream_t stream) {
    (void)in_sizes; (void)n_in; (void)out_size; (void)ws_size;
    const float* x     = (const float*)d_in[0];
    const float* w1    = (const float*)d_in[1];
    const float* gamma = (const float*)d_in[2];
    const float* beta  = (const float*)d_in[3];
    const float* mean  = (const float*)d_in[4];
    const float* var   = (const float*)d_in[5];
    const float* w2    = (const float*)d_in[6];
    const float* b2    = (const float*)d_in[7];
    float* out = (float*)d_out;

    char* ws = (char*)d_ws;
    // x16p: 16*8*60*54*32*2 = 26,542,080 B
    f16* x16p     = (f16*)(ws);
    f16* w16      = (f16*)(ws + 26542080);     // 2,359,296 B
    f16* w2_16    = (f16*)(ws + 28901376);     //    76,800 B
    float* bnscale = (float*)(ws + 28978176);  //     2,048 B
    float* bnshift = (float*)(ws + 28980224);  //     2,048 B
    f16* y16      = (f16*)(ws + 28982272);     // 44,302,336 B (total ~73.3 MB)

    hipMemsetAsync(x16p, 0, 26542080, stream);
    k_prep_x<<<dim3(22, 8, NIMG), 256, 0, stream>>>(x, x16p);
    k_prep_w<<<4608, 256, 0, stream>>>(w1, w2, gamma, beta, mean, var,
                                       w16, w2_16, bnscale, bnshift);
    k_conv1<<<dim3(NIMG * NSPB, 2), 512, 0, stream>>>(x16p, w16, bnscale,
                                                      bnshift, y16);
    k_conv2<<<NIMG * 22, 256, 0, stream>>>(y16, w2_16, b2, out);
}